// Round 1
// baseline (150.176 us; speedup 1.0000x reference)
//
#include <hip/hip_runtime.h>

// ---- problem constants (match reference) ----
constexpr int B = 4, H = 64, W = 64, N = H * W;   // N = 4096
constexpr int NCCH = 8;                            // NC
constexpr int CCH = 5 + NCCH;                      // 13 channels in outputs
constexpr float LINE_W = 30.0f;
constexpr float PULL = 0.5f;
constexpr float PUSH = 1.0f;
constexpr double EPS = 1e-05;
constexpr double DICE_W = 5.0;

// workspace layout (doubles):
//  [b*8 + k], k=0..6 : dice partials per batch: spg,spp,sgg,s2pg,s2pp,s2gg,msum
//  32: focal_sum  33: off_se_sum  34: fg_sum  35: cls_sum
//  36 + (e*B+b)*4 + {0:pull,1:push,2:cs,3:cd}   -> 36..67
constexpr int WS_DOUBLES = 68;

__device__ inline float logsig(float x) {
    // log_sigmoid(x) = min(x,0) - log1p(exp(-|x|))  (stable)
    return fminf(x, 0.f) - log1pf(expf(-fabsf(x)));
}

__device__ inline float wave_reduce(float v) {
    #pragma unroll
    for (int off = 32; off > 0; off >>= 1) v += __shfl_down(v, off, 64);
    return v;
}

__device__ inline void wave_atomic(double* addr, float v) {
    v = wave_reduce(v);
    if ((threadIdx.x & 63) == 0) atomicAdd(addr, (double)v);
}

// ---------------- Kernel A: all elementwise terms ----------------
// grid = B*16 blocks of 256 threads; block (b, tile) handles 256 pixels.
__global__ void elemwise_kernel(const float* __restrict__ outs,
                                const float* __restrict__ gconf,
                                const float* __restrict__ gox,
                                const float* __restrict__ goy,
                                const int*   __restrict__ ign,
                                const int*   __restrict__ fg,
                                const float* __restrict__ gcls,
                                double* __restrict__ ws) {
    const int b   = blockIdx.x >> 4;
    const int n   = ((blockIdx.x & 15) << 8) + threadIdx.x;
    const int pix = b * N + n;
    const float* ob = outs + (size_t)b * CCH * N;

    const float x  = ob[0 * N + n];
    const float g  = gconf[pix];
    const float im = ign[pix] > 0 ? 1.f : 0.f;
    const float ff = fg[pix]  > 0 ? 1.f : 0.f;

    // focal conf
    const float ls  = logsig(x);
    const float lns = logsig(-x);
    const float bce = -(g * ls + (1.f - g) * lns);
    const float p   = expf(-bce);
    const float conf = -(LINE_W * g * ls + (1.f - g) * lns);
    const float om  = 1.f - p;
    const float focal = om * om * conf * im;

    // dice partials (mask = ignore mask)
    const float ps = 1.f / (1.f + expf(-x));
    const float q = 1.f - ps, hh = 1.f - g;
    const float spg = ps * g * im,  spp = ps * ps * im,  sgg = g * g * im;
    const float s2pg = q * hh * im, s2pp = q * q * im,   s2gg = hh * hh * im;

    // offset MSE (both channels, masked by fg)
    const float sox = 1.f / (1.f + expf(-ob[1 * N + n]));
    const float soy = 1.f / (1.f + expf(-ob[2 * N + n]));
    const float dx = sox - gox[pix], dy = soy - goy[pix];
    const float se = (dx * dx + dy * dy) * ff;

    // cls BCE (8 channels, masked by fg)
    float cl = 0.f;
    #pragma unroll
    for (int c = 0; c < NCCH; ++c) {
        const float z  = ob[(5 + c) * N + n];
        const float gc = gcls[((size_t)b * NCCH + c) * N + n];
        cl += -(gc * logsig(z) + (1.f - gc) * logsig(-z));
    }
    cl *= ff;

    double* d = ws + b * 8;
    wave_atomic(d + 0, spg);
    wave_atomic(d + 1, spp);
    wave_atomic(d + 2, sgg);
    wave_atomic(d + 3, s2pg);
    wave_atomic(d + 4, s2pp);
    wave_atomic(d + 5, s2gg);
    wave_atomic(d + 6, im);      // msum per batch (ign_sum derived in finalize)
    wave_atomic(ws + 32, focal);
    wave_atomic(ws + 33, se);
    wave_atomic(ws + 34, ff);
    wave_atomic(ws + 35, cl);
}

// ---------------- Kernel B: pairwise embedding losses ----------------
constexpr int JSPLIT = 4;
constexpr int ITILES = N / 256;   // 16
// grid = 2 * B * ITILES * JSPLIT = 512 blocks of 256 threads
__global__ void emb_kernel(const float* __restrict__ outs,
                           const int* __restrict__ lidx,
                           const int* __restrict__ lid,
                           const int* __restrict__ fg,
                           double* __restrict__ ws) {
    int bx = blockIdx.x;
    const int js = bx & (JSPLIT - 1); bx >>= 2;
    const int it = bx & (ITILES - 1); bx >>= 4;
    const int b  = bx & 3;            bx >>= 2;
    const int e  = bx;                      // 0: emb(ch3,line_idx) 1: emb_id(ch4,line_id)

    const int*   gsrc = e ? lid : lidx;
    const float* pch  = outs + ((size_t)b * CCH + (3 + e)) * N;

    const int i  = it * 256 + threadIdx.x;
    const float pi = pch[i];
    const int   gi = (fg[b * N + i] > 0) ? gsrc[b * N + i] : -1;

    __shared__ float sp[256];
    __shared__ int   sg[256];

    float pull = 0.f, push = 0.f;
    int cs = 0, cd = 0;

    const int j0 = js * (N / JSPLIT);
    for (int jt = 0; jt < (N / JSPLIT) / 256; ++jt) {
        const int j = j0 + jt * 256 + threadIdx.x;
        __syncthreads();
        sp[threadIdx.x] = pch[j];
        sg[threadIdx.x] = (fg[b * N + j] > 0) ? gsrc[b * N + j] : -1;
        __syncthreads();
        if (gi >= 0) {
            #pragma unroll 8
            for (int k = 0; k < 256; ++k) {
                const int gj = sg[k];
                const float d = fabsf(pi - sp[k]);
                const bool valid = gj >= 0;
                const bool same  = (gj == gi);
                if (valid & same)  { pull += fmaxf(d - PULL, 0.f); cs++; }
                else if (valid)    { push += fmaxf(PUSH - d, 0.f); cd++; }
            }
        }
    }

    double* a = ws + 36 + (e * B + b) * 4;
    wave_atomic(a + 0, pull);
    wave_atomic(a + 1, push);
    wave_atomic(a + 2, (float)cs);   // per-wave sums < 2^24, exact in f32
    wave_atomic(a + 3, (float)cd);
}

// ---------------- Kernel C: finalize ----------------
__global__ void finalize_kernel(const double* __restrict__ ws,
                                float* __restrict__ out) {
    double ign_sum = 0.0, dice = 0.0;
    for (int b = 0; b < B; ++b) {
        const double* d = ws + b * 8;
        const double msum = d[6];
        ign_sum += msum;
        const double t = 1.0 - (d[0] + EPS) / (d[1] + d[2] + EPS)
                             - (d[3] + EPS) / (d[4] + d[5] + EPS);
        dice += (msum > 0.0) ? t : 0.0;
    }
    const double focal = ws[32], off_se = ws[33], fgs = ws[34], clss = ws[35];

    const double conf_loss = focal / fmax(ign_sum, 1.0) + DICE_W * dice / B;
    const double off_loss  = off_se / fmax(2.0 * fgs, 1.0);

    double embv[2] = {0.0, 0.0};
    for (int e = 0; e < 2; ++e)
        for (int b = 0; b < B; ++b) {
            const double* a = ws + 36 + (e * B + b) * 4;
            const double cs = a[2], cd = a[3];
            const double pull = a[0] / fmax(cs, 1.0);
            const double push = (cd > 0.0) ? a[1] / fmax(cd, 1.0) : 0.0;
            embv[e] += pull + push;
        }

    const double cls_loss = clss / fmax((double)NCCH * fgs, 1.0);

    const double total = conf_loss + 0.5 * off_loss
                       + embv[0] / B + embv[1] / B + cls_loss;
    out[0] = (float)total;
}

extern "C" void kernel_launch(void* const* d_in, const int* in_sizes, int n_in,
                              void* d_out, int out_size, void* d_ws, size_t ws_size,
                              hipStream_t stream) {
    const float* outs  = (const float*)d_in[0];
    const float* gconf = (const float*)d_in[1];
    const float* gox   = (const float*)d_in[2];
    const float* goy   = (const float*)d_in[3];
    const int*   lidx  = (const int*)d_in[4];
    const int*   ign   = (const int*)d_in[5];
    const int*   fg    = (const int*)d_in[6];
    const int*   lid   = (const int*)d_in[7];
    const float* gcls  = (const float*)d_in[8];
    double* ws = (double*)d_ws;

    hipMemsetAsync(d_ws, 0, WS_DOUBLES * sizeof(double), stream);
    elemwise_kernel<<<B * 16, 256, 0, stream>>>(outs, gconf, gox, goy, ign, fg, gcls, ws);
    emb_kernel<<<2 * B * ITILES * JSPLIT, 256, 0, stream>>>(outs, lidx, lid, fg, ws);
    finalize_kernel<<<1, 1, 0, stream>>>(ws, (float*)d_out);
}

// Round 2
// 68.512 us; speedup vs baseline: 2.1920x; 2.1920x over previous
//
#include <hip/hip_runtime.h>

// ---- problem constants (match reference) ----
constexpr int B = 4, H = 64, W = 64, N = H * W;   // N = 4096
constexpr int NCCH = 8;                            // NC
constexpr int CCH = 5 + NCCH;                      // 13 channels in outputs
constexpr float LINE_W = 30.0f;
constexpr double EPS = 1e-05;
constexpr double DICE_W = 5.0;

// ---- workspace layout (doubles) ----
//  [b*8 + k], k=0..6 : dice partials per batch: spg,spp,sgg,s2pg,s2pp,s2gg,msum
//  32: focal_sum  33: off_se_sum  34: fg_sum  35: cls_sum
//  40 + (e*4+b)*8 + c : class histogram counts (c in 0..7)          -> 40..103
//  104 + (eb*256 + blk)*2 + q : emb per-block partials (q0=tot,q1=same) -> 104..4199
constexpr int WS_ACC_DOUBLES = 104;      // region that must be zeroed
constexpr int WS_PART = 104;

__device__ inline float logsig(float x) {
    return fminf(x, 0.f) - log1pf(expf(-fabsf(x)));
}

__device__ inline float wave_reduce(float v) {
    #pragma unroll
    for (int off = 32; off > 0; off >>= 1) v += __shfl_down(v, off, 64);
    return v;
}
__device__ inline double wave_reduce_d(double v) {
    #pragma unroll
    for (int off = 32; off > 0; off >>= 1) v += __shfl_down(v, off, 64);
    return v;
}

// ---------------- Kernel A: elementwise terms + class histograms ----------------
// grid = B*16 blocks of 256 threads
__global__ __launch_bounds__(256) void elemwise_kernel(
        const float* __restrict__ outs,
        const float* __restrict__ gconf,
        const float* __restrict__ gox,
        const float* __restrict__ goy,
        const int*   __restrict__ lidx,
        const int*   __restrict__ ign,
        const int*   __restrict__ fg,
        const int*   __restrict__ lid,
        const float* __restrict__ gcls,
        double* __restrict__ ws) {
    const int b   = blockIdx.x >> 4;
    const int n   = ((blockIdx.x & 15) << 8) + threadIdx.x;
    const int pix = b * N + n;
    const float* ob = outs + (size_t)b * CCH * N;

    __shared__ int hh[16];
    if (threadIdx.x < 16) hh[threadIdx.x] = 0;

    const float x  = ob[0 * N + n];
    const float g  = gconf[pix];
    const float im = ign[pix] > 0 ? 1.f : 0.f;
    const int   fgi = fg[pix];
    const float ff = fgi > 0 ? 1.f : 0.f;

    // focal conf
    const float ls  = logsig(x);
    const float lns = logsig(-x);
    const float bce = -(g * ls + (1.f - g) * lns);
    const float p   = expf(-bce);
    const float conf = -(LINE_W * g * ls + (1.f - g) * lns);
    const float om  = 1.f - p;
    const float focal = om * om * conf * im;

    // dice partials (mask = ignore mask)
    const float ps = 1.f / (1.f + expf(-x));
    const float q = 1.f - ps, hhf = 1.f - g;
    const float spg = ps * g * im,  spp = ps * ps * im,  sgg = g * g * im;
    const float s2pg = q * hhf * im, s2pp = q * q * im,  s2gg = hhf * hhf * im;

    // offset MSE
    const float sox = 1.f / (1.f + expf(-ob[1 * N + n]));
    const float soy = 1.f / (1.f + expf(-ob[2 * N + n]));
    const float dx = sox - gox[pix], dy = soy - goy[pix];
    const float se = (dx * dx + dy * dy) * ff;

    // cls BCE (8 channels)
    float cl = 0.f;
    #pragma unroll
    for (int c = 0; c < NCCH; ++c) {
        const float z  = ob[(5 + c) * N + n];
        const float gc = gcls[((size_t)b * NCCH + c) * N + n];
        cl += -(gc * logsig(z) + (1.f - gc) * logsig(-z));
    }
    cl *= ff;

    // class histograms over fg pixels (for cs/cd counts)
    __syncthreads();
    if (fgi > 0) {
        atomicAdd(&hh[lidx[pix]], 1);
        atomicAdd(&hh[8 + lid[pix]], 1);
    }

    // block reduction of the 11 float quantities
    float vals[11] = {spg, spp, sgg, s2pg, s2pp, s2gg, im, focal, se, ff, cl};
    __shared__ float red[4][11];
    const int wv = threadIdx.x >> 6, ln = threadIdx.x & 63;
    #pragma unroll
    for (int q2 = 0; q2 < 11; ++q2) {
        const float r = wave_reduce(vals[q2]);
        if (ln == 0) red[wv][q2] = r;
    }
    __syncthreads();
    if (threadIdx.x == 0) {
        #pragma unroll
        for (int q2 = 0; q2 < 11; ++q2) {
            const double s = (double)red[0][q2] + red[1][q2] + red[2][q2] + red[3][q2];
            double* dst;
            if (q2 < 7)       dst = ws + b * 8 + q2;
            else              dst = ws + 32 + (q2 - 7);
            atomicAdd(dst, s);
        }
    }
    if (threadIdx.x < 16) {
        const int e = threadIdx.x >> 3, c = threadIdx.x & 7;
        const int cnt = hh[threadIdx.x];
        if (cnt) atomicAdd(ws + 40 + (e * 4 + b) * 8 + c, (double)cnt);
    }
}

// ---------------- Kernel B: pairwise embedding (branchless, readlane bcast) ----
// grid = 2048 blocks of 256 threads: bx -> eb(3) | it(4) | js(4)
__global__ __launch_bounds__(256) void emb_kernel(
        const float* __restrict__ outs,
        const int* __restrict__ lidx,
        const int* __restrict__ lid,
        const int* __restrict__ fg,
        double* __restrict__ ws) {
    const int bx = blockIdx.x;
    const int eb = bx >> 8;
    const int e  = eb >> 2, b = eb & 3;
    const int it = (bx >> 4) & 15, js = bx & 15;

    const int*   gsrc = e ? lid : lidx;
    const float* pch  = outs + ((size_t)b * CCH + 3 + e) * N;

    const int i = it * 256 + threadIdx.x;
    const bool vi = fg[b * N + i] > 0;
    const float pi = vi ? pch[i] : 1e30f;
    const int   gi = vi ? gsrc[b * N + i] : -2;

    float tot = 0.f, sme = 0.f;
    const int j0 = js * 256;
    const int ln = threadIdx.x & 63;

    for (int c = 0; c < 4; ++c) {
        const int j = j0 + c * 64 + ln;
        const bool vj = fg[b * N + j] > 0;
        const float vp = vj ? pch[j] : 1e30f;
        const int   vg = vj ? gsrc[b * N + j] : -2;
        #pragma unroll
        for (int k = 0; k < 64; ++k) {
            const float sp = __uint_as_float(
                __builtin_amdgcn_readlane(__float_as_uint(vp), k));
            const int sg = __builtin_amdgcn_readlane(vg, k);
            const float dd = fabsf(pi - sp);
            const bool same = (gi == sg);
            const float sel = same ? (dd - 0.5f) : (1.0f - dd);
            const float h = fmaxf(sel, 0.f);
            tot += h;
            sme += same ? h : 0.f;
        }
    }

    // block reduce (tot, sme) -> per-block partial slots (no atomics)
    __shared__ float red[4][2];
    const int wv = threadIdx.x >> 6;
    const float rt = wave_reduce(tot);
    const float rs = wave_reduce(sme);
    if (ln == 0) { red[wv][0] = rt; red[wv][1] = rs; }
    __syncthreads();
    if (threadIdx.x == 0) {
        const int blk = bx & 255;
        double* dst = ws + WS_PART + (eb * 256 + blk) * 2;
        dst[0] = (double)red[0][0] + red[1][0] + red[2][0] + red[3][0];
        dst[1] = (double)red[0][1] + red[1][1] + red[2][1] + red[3][1];
    }
}

// ---------------- Kernel C: finalize (1 block, 256 threads) ----------------
__global__ __launch_bounds__(256) void finalize_kernel(
        const double* __restrict__ ws, float* __restrict__ out) {
    __shared__ double sums[16];   // [eb][q]
    const int ln = threadIdx.x & 63, wv = threadIdx.x >> 6;
    __shared__ double red[4];
    for (int r = 0; r < 16; ++r) {
        const int eb = r >> 1, q = r & 1;
        double v = ws[WS_PART + (eb * 256 + threadIdx.x) * 2 + q];
        v = wave_reduce_d(v);
        if (ln == 0) red[wv] = v;
        __syncthreads();
        if (threadIdx.x == 0) sums[r] = red[0] + red[1] + red[2] + red[3];
        __syncthreads();
    }
    if (threadIdx.x != 0) return;

    double ign_sum = 0.0, dice = 0.0;
    for (int b = 0; b < B; ++b) {
        const double* d = ws + b * 8;
        const double msum = d[6];
        ign_sum += msum;
        const double t = 1.0 - (d[0] + EPS) / (d[1] + d[2] + EPS)
                             - (d[3] + EPS) / (d[4] + d[5] + EPS);
        dice += (msum > 0.0) ? t : 0.0;
    }
    const double focal = ws[32], off_se = ws[33], fgs = ws[34], clss = ws[35];
    const double conf_loss = focal / fmax(ign_sum, 1.0) + DICE_W * dice / B;
    const double off_loss  = off_se / fmax(2.0 * fgs, 1.0);

    double embv[2] = {0.0, 0.0};
    for (int e = 0; e < 2; ++e)
        for (int b = 0; b < B; ++b) {
            const int eb = e * 4 + b;
            double cs = 0.0, nv = 0.0;
            for (int c = 0; c < 8; ++c) {
                const double nc = ws[40 + eb * 8 + c];
                cs += nc * nc; nv += nc;
            }
            const double cd = nv * nv - cs;
            const double tot = sums[eb * 2 + 0], same = sums[eb * 2 + 1];
            const double pull = same / fmax(cs, 1.0);
            const double push = (cd > 0.0) ? (tot - same) / fmax(cd, 1.0) : 0.0;
            embv[e] += pull + push;
        }

    const double cls_loss = clss / fmax((double)NCCH * fgs, 1.0);
    const double total = conf_loss + 0.5 * off_loss
                       + embv[0] / B + embv[1] / B + cls_loss;
    out[0] = (float)total;
}

extern "C" void kernel_launch(void* const* d_in, const int* in_sizes, int n_in,
                              void* d_out, int out_size, void* d_ws, size_t ws_size,
                              hipStream_t stream) {
    const float* outs  = (const float*)d_in[0];
    const float* gconf = (const float*)d_in[1];
    const float* gox   = (const float*)d_in[2];
    const float* goy   = (const float*)d_in[3];
    const int*   lidx  = (const int*)d_in[4];
    const int*   ign   = (const int*)d_in[5];
    const int*   fg    = (const int*)d_in[6];
    const int*   lid   = (const int*)d_in[7];
    const float* gcls  = (const float*)d_in[8];
    double* ws = (double*)d_ws;

    hipMemsetAsync(d_ws, 0, WS_ACC_DOUBLES * sizeof(double), stream);
    elemwise_kernel<<<B * 16, 256, 0, stream>>>(outs, gconf, gox, goy, lidx, ign, fg, lid, gcls, ws);
    emb_kernel<<<2048, 256, 0, stream>>>(outs, lidx, lid, fg, ws);
    finalize_kernel<<<1, 256, 0, stream>>>(ws, (float*)d_out);
}